// Round 14
// baseline (93.524 us; speedup 1.0000x reference)
//
#include <hip/hip_runtime.h>
#include <cstdint>
#include <cstddef>

#define NB 20000
#define NT 1000
#define P_PAIRS 50000
#define MARGIN 2.0f
#define RANK_W 0.3f
#define NEG_SENT -1e9f

#define BLOCK 256
#define ROWS_PB 16
#define NBLOCKS (NB / ROWS_PB)      // 1250
#define PB4 (P_PAIRS / 4)
#define BUCKET_CAP 256              // expected ~40 pairs/block
#define MROW_W 33                   // padded mask words per row

// ---------------- workspace layout (bytes) ----------------
// [0,    5000)  int   counts[1250]
// [5000] float sq_total   [5004] float rsum
// [5008] uint  nrp        [5012] uint  ticket
// zero range: [0, 5016)
// [5120, 1285120) int lists[1250][256]  (packed (localRow<<10)|t; no init needed)

__global__ void zero_ctrl_kernel(unsigned int* __restrict__ ws) {
    int i = blockIdx.x * blockDim.x + threadIdx.x;
    if (i < 1254) ws[i] = 0u;
}

__global__ __launch_bounds__(256)
void scatter_kernel(const int* __restrict__ pb,
                    const int* __restrict__ pt,
                    int* __restrict__ counts,
                    int* __restrict__ lists) {
    int p = blockIdx.x * 256 + threadIdx.x;
    if (p >= P_PAIRS) return;
    int b = pb[p];
    int t = pt[p];
    int blk = b >> 4;                       // b / ROWS_PB
    int idx = atomicAdd(&counts[blk], 1);
    if (idx < BUCKET_CAP) lists[blk * BUCKET_CAP + idx] = ((b & 15) << 10) | t;
}

// branchless sorted-desc insert of x into (t0>=t1>=t2>=t3>=t4)
#define INSERT5(x)                                        \
    {                                                     \
        float _x = (x);                                   \
        float n0 = fmaxf(t0, _x), s0_ = fminf(t0, _x);    \
        float n1 = fmaxf(t1, s0_), s1_ = fminf(t1, s0_);  \
        float n2 = fmaxf(t2, s1_), s2_ = fminf(t2, s1_);  \
        float n3 = fmaxf(t3, s2_), s3_ = fminf(t3, s2_);  \
        float n4 = fmaxf(t4, s3_);                        \
        t0 = n0; t1 = n1; t2 = n2; t3 = n3; t4 = n4;      \
    }

#define PROC1(xv, lab)                                              \
    {                                                               \
        float _x = (xv);                                            \
        int _lab = (lab);                                           \
        float _s = __builtin_amdgcn_rcpf(1.0f + __expf(-_x));       \
        float _d = (float)_lab - _s;                                \
        sq = fmaf(_d, _d, sq);                                      \
        pcount += _lab;                                             \
        float _xx = _lab ? NEG_SENT : _x;                           \
        INSERT5(_xx);                                               \
    }

#define PROC4(v, bits)                        \
    PROC1((v).x, (int)(((bits) >> 0) & 1u));  \
    PROC1((v).y, (int)(((bits) >> 1) & 1u));  \
    PROC1((v).z, (int)(((bits) >> 2) & 1u));  \
    PROC1((v).w, (int)(((bits) >> 3) & 1u));

// K1: 16 rows/block, 1250 blocks. Mask from this block's bucket (no scan).
// Row pass -> local pair contributions -> global atomics + ticket finalize.
__global__ __launch_bounds__(BLOCK)
void fused_row_pair_kernel(const float* __restrict__ scores,
                           const int* __restrict__ pb,
                           const int* __restrict__ pt,
                           const int* __restrict__ counts,
                           const int* __restrict__ lists,
                           float* __restrict__ sq_total,
                           float* __restrict__ rsum,
                           unsigned int* __restrict__ nrp,
                           unsigned int* __restrict__ ticket,
                           float* __restrict__ out) {
    const int tid  = threadIdx.x;
    const int lane = tid & 63;
    const int wib  = tid >> 6;          // wave in block 0..3
    const int grp  = lane >> 4;         // group in wave  0..3
    const int gl   = lane & 15;         // lane in group  0..15
    const int rowBase = blockIdx.x * ROWS_PB;

    __shared__ unsigned int smask[ROWS_PB * MROW_W];
    __shared__ float  stop5[ROWS_PB][5];
    __shared__ int    snn[ROWS_PB];
    __shared__ int    plist[BUCKET_CAP];
    __shared__ float  bsq[ROWS_PB];
    __shared__ float  sc[4];
    __shared__ unsigned int sv[4];

    // ---- Phase 1: zero LDS mask ----
    for (int i = tid; i < ROWS_PB * MROW_W; i += BLOCK) smask[i] = 0u;
    __syncthreads();

    // ---- Phase 2: load this block's bucket; build LDS mask ----
    const int rawCnt = counts[blockIdx.x];
    const bool overflow = rawCnt > BUCKET_CAP;
    const int cnt = overflow ? 0 : rawCnt;
    if (tid < cnt) {
        int e = lists[blockIdx.x * BUCKET_CAP + tid];
        plist[tid] = e;
        int lr = e >> 10, t = e & 1023;
        atomicOr(&smask[lr * MROW_W + (t >> 5)], 1u << (t & 31));
    }
    if (overflow) {
        // adversarial-only fallback: full pair scan to build the mask
        const int4* pb4 = reinterpret_cast<const int4*>(pb);
        for (int i = tid; i < PB4; i += BLOCK) {
            int4 v = pb4[i];
            int bs[4] = {v.x, v.y, v.z, v.w};
            #pragma unroll
            for (int j = 0; j < 4; ++j) {
                unsigned int d = (unsigned int)(bs[j] - rowBase);
                if (d < (unsigned int)ROWS_PB) {
                    int t = pt[i * 4 + j];
                    atomicOr(&smask[d * MROW_W + (t >> 5)], 1u << (t & 31));
                }
            }
        }
    }
    __syncthreads();

    // ---- Phase 3: row pass (16 lanes/row; mask from LDS) ----
    const int localRow = wib * 4 + grp;
    const int row = rowBase + localRow;
    const float4* rowp = reinterpret_cast<const float4*>(scores + (size_t)row * NT);
    const unsigned int* mrow = smask + localRow * MROW_W;
    const int wb = gl >> 3;
    const int sh = (gl & 7) * 4;

    float t0 = NEG_SENT, t1 = NEG_SENT, t2 = NEG_SENT, t3 = NEG_SENT, t4 = NEG_SENT;
    float sq = 0.0f;
    int pcount = 0;

    {
        float4 v0 = rowp[gl      ];
        float4 v1 = rowp[gl +  16];
        float4 v2 = rowp[gl +  32];
        float4 v3 = rowp[gl +  48];
        unsigned int b0 = (mrow[wb     ] >> sh) & 0xFu;
        unsigned int b1 = (mrow[wb +  2] >> sh) & 0xFu;
        unsigned int b2 = (mrow[wb +  4] >> sh) & 0xFu;
        unsigned int b3 = (mrow[wb +  6] >> sh) & 0xFu;
        PROC4(v0, b0); PROC4(v1, b1); PROC4(v2, b2); PROC4(v3, b3);
    }
    {
        float4 v0 = rowp[gl +  64];
        float4 v1 = rowp[gl +  80];
        float4 v2 = rowp[gl +  96];
        float4 v3 = rowp[gl + 112];
        unsigned int b0 = (mrow[wb +  8] >> sh) & 0xFu;
        unsigned int b1 = (mrow[wb + 10] >> sh) & 0xFu;
        unsigned int b2 = (mrow[wb + 12] >> sh) & 0xFu;
        unsigned int b3 = (mrow[wb + 14] >> sh) & 0xFu;
        PROC4(v0, b0); PROC4(v1, b1); PROC4(v2, b2); PROC4(v3, b3);
    }
    {
        float4 v0 = rowp[gl + 128];
        float4 v1 = rowp[gl + 144];
        float4 v2 = rowp[gl + 160];
        float4 v3 = rowp[gl + 176];
        unsigned int b0 = (mrow[wb + 16] >> sh) & 0xFu;
        unsigned int b1 = (mrow[wb + 18] >> sh) & 0xFu;
        unsigned int b2 = (mrow[wb + 20] >> sh) & 0xFu;
        unsigned int b3 = (mrow[wb + 22] >> sh) & 0xFu;
        PROC4(v0, b0); PROC4(v1, b1); PROC4(v2, b2); PROC4(v3, b3);
    }
    {
        float4 v0 = rowp[gl + 192];
        float4 v1 = rowp[gl + 208];
        float4 v2 = rowp[gl + 224];
        unsigned int b0 = (mrow[wb + 24] >> sh) & 0xFu;
        unsigned int b1 = (mrow[wb + 26] >> sh) & 0xFu;
        unsigned int b2 = (mrow[wb + 28] >> sh) & 0xFu;
        PROC4(v0, b0); PROC4(v1, b1); PROC4(v2, b2);
    }
    if (gl < 10) {   // tail (250 float4 per row)
        float4 v = rowp[gl + 240];
        unsigned int bt = (mrow[wb + 30] >> sh) & 0xFu;
        PROC4(v, bt);
    }

    #pragma unroll
    for (int off = 8; off >= 1; off >>= 1) {
        float b0 = __shfl_xor(t0, off, 16);
        float b1 = __shfl_xor(t1, off, 16);
        float b2 = __shfl_xor(t2, off, 16);
        float b3 = __shfl_xor(t3, off, 16);
        float b4 = __shfl_xor(t4, off, 16);
        sq     += __shfl_xor(sq, off, 16);
        pcount += __shfl_xor(pcount, off, 16);

        float m1  = fminf(t0, b0);
        float m2a = fminf(t1, b0), m2b = fminf(t0, b1);
        float m3a = fminf(t2, b0), m3b = fminf(t1, b1), m3c = fminf(t0, b2);
        float m4a = fminf(t3, b0), m4b = fminf(t2, b1), m4c = fminf(t1, b2), m4d = fminf(t0, b3);
        float c0 = fmaxf(t0, b0);
        float c1 = fmaxf(fmaxf(t1, b1), m1);
        float c2 = fmaxf(fmaxf(t2, b2), fmaxf(m2a, m2b));
        float c3 = fmaxf(fmaxf(t3, b3), fmaxf(fmaxf(m3a, m3b), m3c));
        float c4 = fmaxf(fmaxf(t4, b4), fmaxf(fmaxf(m4a, m4b), fmaxf(m4c, m4d)));
        t0 = c0; t1 = c1; t2 = c2; t3 = c3; t4 = c4;
    }

    if (gl == 0) {
        stop5[localRow][0] = t0; stop5[localRow][1] = t1; stop5[localRow][2] = t2;
        stop5[localRow][3] = t3; stop5[localRow][4] = t4;
        snn[localRow] = NT - pcount;
        bsq[localRow] = sq;
    }
    __syncthreads();

    // ---- Phase 4: pair contributions ----
    float c = 0.0f;
    unsigned int valid = 0;
    if (!overflow) {
        for (int k = tid; k < cnt; k += BLOCK) {
            int e = plist[k];
            int lr = e >> 10, t = e & 1023;
            float pos = scores[(size_t)(rowBase + lr) * NT + t];
            #pragma unroll
            for (int q = 0; q < 5; ++q) {
                float contrib = MARGIN - (pos - stop5[lr][q]);
                c += contrib > 0.0f ? contrib : 0.0f;
            }
            int nn = snn[lr];
            valid += (unsigned int)(nn < 5 ? nn : 5);
        }
    } else {
        const int4* pb4 = reinterpret_cast<const int4*>(pb);
        for (int i = tid; i < PB4; i += BLOCK) {
            int4 v = pb4[i];
            int bs[4] = {v.x, v.y, v.z, v.w};
            #pragma unroll
            for (int j = 0; j < 4; ++j) {
                unsigned int d = (unsigned int)(bs[j] - rowBase);
                if (d < (unsigned int)ROWS_PB) {
                    int t = pt[i * 4 + j];
                    float pos = scores[(size_t)(rowBase + d) * NT + t];
                    #pragma unroll
                    for (int q = 0; q < 5; ++q) {
                        float contrib = MARGIN - (pos - stop5[d][q]);
                        c += contrib > 0.0f ? contrib : 0.0f;
                    }
                    int nn = snn[d];
                    valid += (unsigned int)(nn < 5 ? nn : 5);
                }
            }
        }
    }

    #pragma unroll
    for (int off = 32; off >= 1; off >>= 1) {
        c     += __shfl_xor(c, off);
        valid += __shfl_xor(valid, off);
    }
    if ((tid & 63) == 0) { sc[wib] = c; sv[wib] = valid; }
    __syncthreads();

    // ---- Phase 5: global accumulate + ticket finalize (R7-proven) ----
    if (tid == 0) {
        float s = 0.0f;
        #pragma unroll
        for (int k = 0; k < ROWS_PB; ++k) s += bsq[k];
        atomicAdd(sq_total, s);
        atomicAdd(rsum, sc[0] + sc[1] + sc[2] + sc[3]);
        atomicAdd(nrp,  sv[0] + sv[1] + sv[2] + sv[3]);
        __threadfence();
        unsigned int done = atomicAdd(ticket, 1u);
        if (done == NBLOCKS - 1) {
            float sqt = atomicAdd(sq_total, 0.0f);
            float rs  = atomicAdd(rsum, 0.0f);
            unsigned int n = atomicAdd(nrp, 0u);
            float loss = 0.5f * sqt / 2.0e7f;        // NB*NT = 2e7
            if (n > 0) loss += RANK_W * rs / (float)n;
            out[0] = loss;
        }
    }
}

extern "C" void kernel_launch(void* const* d_in, const int* in_sizes, int n_in,
                              void* d_out, int out_size, void* d_ws, size_t ws_size,
                              hipStream_t stream) {
    const float* scores = (const float*)d_in[0];
    const int*   pb     = (const int*)d_in[1];
    const int*   pt     = (const int*)d_in[2];
    float*       out    = (float*)d_out;

    char* ws = (char*)d_ws;
    int*          counts   = (int*)ws;
    float*        sq_total = (float*)(ws + 5000);
    float*        rsum     = (float*)(ws + 5004);
    unsigned int* nrp      = (unsigned int*)(ws + 5008);
    unsigned int* ticket   = (unsigned int*)(ws + 5012);
    int*          lists    = (int*)(ws + 5120);

    zero_ctrl_kernel<<<5, 256, 0, stream>>>((unsigned int*)ws);
    scatter_kernel<<<(P_PAIRS + 255) / 256, 256, 0, stream>>>(pb, pt, counts, lists);
    fused_row_pair_kernel<<<NBLOCKS, BLOCK, 0, stream>>>(
        scores, pb, pt, counts, lists, sq_total, rsum, nrp, ticket, out);
}

// Round 15
// 92.309 us; speedup vs baseline: 1.0132x; 1.0132x over previous
//
#include <hip/hip_runtime.h>
#include <cstdint>
#include <cstddef>

#define NB 20000
#define NT 1000
#define P_PAIRS 50000
#define MARGIN 2.0f
#define RANK_W 0.3f
#define NEG_SENT -1e9f

#define BLOCK 256
#define ROWS_PB 16
#define NBLOCKS (NB / ROWS_PB)      // 1250
#define PB4 (P_PAIRS / 4)
#define BUCKET_CAP 256              // expected ~40 pairs/block
#define MROW_W 33                   // padded mask words per row

// ---------------- workspace layout (bytes) ----------------
// [0,    5000)  int   counts[1250]
// [5000] float sq_total   [5004] float rsum
// [5008] uint  nrp        [5012] uint  ticket
// zero range: [0, 5016)
// [5120, 1285120) int lists[1250][256]  (packed (localRow<<10)|t; no init needed)

__global__ void zero_ctrl_kernel(unsigned int* __restrict__ ws) {
    int i = blockIdx.x * blockDim.x + threadIdx.x;
    if (i < 1254) ws[i] = 0u;
}

__global__ __launch_bounds__(256)
void scatter_kernel(const int* __restrict__ pb,
                    const int* __restrict__ pt,
                    int* __restrict__ counts,
                    int* __restrict__ lists) {
    int p = blockIdx.x * 256 + threadIdx.x;
    if (p >= P_PAIRS) return;
    int b = pb[p];
    int t = pt[p];
    int blk = b >> 4;                       // b / ROWS_PB
    int idx = atomicAdd(&counts[blk], 1);
    if (idx < BUCKET_CAP) lists[blk * BUCKET_CAP + idx] = ((b & 15) << 10) | t;
}

// branchless sorted-desc insert of x into (t0>=t1>=t2>=t3>=t4)
#define INSERT5(x)                                        \
    {                                                     \
        float _x = (x);                                   \
        float n0 = fmaxf(t0, _x), s0_ = fminf(t0, _x);    \
        float n1 = fmaxf(t1, s0_), s1_ = fminf(t1, s0_);  \
        float n2 = fmaxf(t2, s1_), s2_ = fminf(t2, s1_);  \
        float n3 = fmaxf(t3, s2_), s3_ = fminf(t3, s2_);  \
        float n4 = fmaxf(t4, s3_);                        \
        t0 = n0; t1 = n1; t2 = n2; t3 = n3; t4 = n4;      \
    }

#define PROC1(xv, lab)                                              \
    {                                                               \
        float _x = (xv);                                            \
        int _lab = (lab);                                           \
        float _s = __builtin_amdgcn_rcpf(1.0f + __expf(-_x));       \
        float _d = (float)_lab - _s;                                \
        sq = fmaf(_d, _d, sq);                                      \
        pcount += _lab;                                             \
        float _xx = _lab ? NEG_SENT : _x;                           \
        INSERT5(_xx);                                               \
    }

#define PROC4(v, bits)                        \
    PROC1((v).x, (int)(((bits) >> 0) & 1u));  \
    PROC1((v).y, (int)(((bits) >> 1) & 1u));  \
    PROC1((v).z, (int)(((bits) >> 2) & 1u));  \
    PROC1((v).w, (int)(((bits) >> 3) & 1u));

// K1: 16 rows/block, 1250 blocks. Mask from this block's bucket (no scan).
// Row pass -> pair contributions -> FENCE-FREE atomic accumulate + ticket.
__global__ __launch_bounds__(BLOCK)
void fused_row_pair_kernel(const float* __restrict__ scores,
                           const int* __restrict__ pb,
                           const int* __restrict__ pt,
                           const int* __restrict__ counts,
                           const int* __restrict__ lists,
                           float* __restrict__ sq_total,
                           float* __restrict__ rsum,
                           unsigned int* __restrict__ nrp,
                           unsigned int* __restrict__ ticket,
                           float* __restrict__ out) {
    const int tid  = threadIdx.x;
    const int lane = tid & 63;
    const int wib  = tid >> 6;          // wave in block 0..3
    const int grp  = lane >> 4;         // group in wave  0..3
    const int gl   = lane & 15;         // lane in group  0..15
    const int rowBase = blockIdx.x * ROWS_PB;

    __shared__ unsigned int smask[ROWS_PB * MROW_W];
    __shared__ float  stop5[ROWS_PB][5];
    __shared__ int    snn[ROWS_PB];
    __shared__ int    plist[BUCKET_CAP];
    __shared__ float  bsq[ROWS_PB];
    __shared__ float  sc[4];
    __shared__ unsigned int sv[4];

    // ---- Phase 1: zero LDS mask ----
    for (int i = tid; i < ROWS_PB * MROW_W; i += BLOCK) smask[i] = 0u;
    __syncthreads();

    // ---- Phase 2: load this block's bucket; build LDS mask ----
    const int rawCnt = counts[blockIdx.x];
    const bool overflow = rawCnt > BUCKET_CAP;
    const int cnt = overflow ? 0 : rawCnt;
    if (tid < cnt) {
        int e = lists[blockIdx.x * BUCKET_CAP + tid];
        plist[tid] = e;
        int lr = e >> 10, t = e & 1023;
        atomicOr(&smask[lr * MROW_W + (t >> 5)], 1u << (t & 31));
    }
    if (overflow) {
        // adversarial-only fallback: full pair scan to build the mask
        const int4* pb4 = reinterpret_cast<const int4*>(pb);
        for (int i = tid; i < PB4; i += BLOCK) {
            int4 v = pb4[i];
            int bs[4] = {v.x, v.y, v.z, v.w};
            #pragma unroll
            for (int j = 0; j < 4; ++j) {
                unsigned int d = (unsigned int)(bs[j] - rowBase);
                if (d < (unsigned int)ROWS_PB) {
                    int t = pt[i * 4 + j];
                    atomicOr(&smask[d * MROW_W + (t >> 5)], 1u << (t & 31));
                }
            }
        }
    }
    __syncthreads();

    // ---- Phase 3: row pass (16 lanes/row; mask from LDS) ----
    const int localRow = wib * 4 + grp;
    const int row = rowBase + localRow;
    const float4* rowp = reinterpret_cast<const float4*>(scores + (size_t)row * NT);
    const unsigned int* mrow = smask + localRow * MROW_W;
    const int wb = gl >> 3;
    const int sh = (gl & 7) * 4;

    float t0 = NEG_SENT, t1 = NEG_SENT, t2 = NEG_SENT, t3 = NEG_SENT, t4 = NEG_SENT;
    float sq = 0.0f;
    int pcount = 0;

    {
        float4 v0 = rowp[gl      ];
        float4 v1 = rowp[gl +  16];
        float4 v2 = rowp[gl +  32];
        float4 v3 = rowp[gl +  48];
        unsigned int b0 = (mrow[wb     ] >> sh) & 0xFu;
        unsigned int b1 = (mrow[wb +  2] >> sh) & 0xFu;
        unsigned int b2 = (mrow[wb +  4] >> sh) & 0xFu;
        unsigned int b3 = (mrow[wb +  6] >> sh) & 0xFu;
        PROC4(v0, b0); PROC4(v1, b1); PROC4(v2, b2); PROC4(v3, b3);
    }
    {
        float4 v0 = rowp[gl +  64];
        float4 v1 = rowp[gl +  80];
        float4 v2 = rowp[gl +  96];
        float4 v3 = rowp[gl + 112];
        unsigned int b0 = (mrow[wb +  8] >> sh) & 0xFu;
        unsigned int b1 = (mrow[wb + 10] >> sh) & 0xFu;
        unsigned int b2 = (mrow[wb + 12] >> sh) & 0xFu;
        unsigned int b3 = (mrow[wb + 14] >> sh) & 0xFu;
        PROC4(v0, b0); PROC4(v1, b1); PROC4(v2, b2); PROC4(v3, b3);
    }
    {
        float4 v0 = rowp[gl + 128];
        float4 v1 = rowp[gl + 144];
        float4 v2 = rowp[gl + 160];
        float4 v3 = rowp[gl + 176];
        unsigned int b0 = (mrow[wb + 16] >> sh) & 0xFu;
        unsigned int b1 = (mrow[wb + 18] >> sh) & 0xFu;
        unsigned int b2 = (mrow[wb + 20] >> sh) & 0xFu;
        unsigned int b3 = (mrow[wb + 22] >> sh) & 0xFu;
        PROC4(v0, b0); PROC4(v1, b1); PROC4(v2, b2); PROC4(v3, b3);
    }
    {
        float4 v0 = rowp[gl + 192];
        float4 v1 = rowp[gl + 208];
        float4 v2 = rowp[gl + 224];
        unsigned int b0 = (mrow[wb + 24] >> sh) & 0xFu;
        unsigned int b1 = (mrow[wb + 26] >> sh) & 0xFu;
        unsigned int b2 = (mrow[wb + 28] >> sh) & 0xFu;
        PROC4(v0, b0); PROC4(v1, b1); PROC4(v2, b2);
    }
    if (gl < 10) {   // tail (250 float4 per row)
        float4 v = rowp[gl + 240];
        unsigned int bt = (mrow[wb + 30] >> sh) & 0xFu;
        PROC4(v, bt);
    }

    #pragma unroll
    for (int off = 8; off >= 1; off >>= 1) {
        float b0 = __shfl_xor(t0, off, 16);
        float b1 = __shfl_xor(t1, off, 16);
        float b2 = __shfl_xor(t2, off, 16);
        float b3 = __shfl_xor(t3, off, 16);
        float b4 = __shfl_xor(t4, off, 16);
        sq     += __shfl_xor(sq, off, 16);
        pcount += __shfl_xor(pcount, off, 16);

        float m1  = fminf(t0, b0);
        float m2a = fminf(t1, b0), m2b = fminf(t0, b1);
        float m3a = fminf(t2, b0), m3b = fminf(t1, b1), m3c = fminf(t0, b2);
        float m4a = fminf(t3, b0), m4b = fminf(t2, b1), m4c = fminf(t1, b2), m4d = fminf(t0, b3);
        float c0 = fmaxf(t0, b0);
        float c1 = fmaxf(fmaxf(t1, b1), m1);
        float c2 = fmaxf(fmaxf(t2, b2), fmaxf(m2a, m2b));
        float c3 = fmaxf(fmaxf(t3, b3), fmaxf(fmaxf(m3a, m3b), m3c));
        float c4 = fmaxf(fmaxf(t4, b4), fmaxf(fmaxf(m4a, m4b), fmaxf(m4c, m4d)));
        t0 = c0; t1 = c1; t2 = c2; t3 = c3; t4 = c4;
    }

    if (gl == 0) {
        stop5[localRow][0] = t0; stop5[localRow][1] = t1; stop5[localRow][2] = t2;
        stop5[localRow][3] = t3; stop5[localRow][4] = t4;
        snn[localRow] = NT - pcount;
        bsq[localRow] = sq;
    }
    __syncthreads();

    // ---- Phase 4: pair contributions ----
    float c = 0.0f;
    unsigned int valid = 0;
    if (!overflow) {
        for (int k = tid; k < cnt; k += BLOCK) {
            int e = plist[k];
            int lr = e >> 10, t = e & 1023;
            float pos = scores[(size_t)(rowBase + lr) * NT + t];
            #pragma unroll
            for (int q = 0; q < 5; ++q) {
                float contrib = MARGIN - (pos - stop5[lr][q]);
                c += contrib > 0.0f ? contrib : 0.0f;
            }
            int nn = snn[lr];
            valid += (unsigned int)(nn < 5 ? nn : 5);
        }
    } else {
        const int4* pb4 = reinterpret_cast<const int4*>(pb);
        for (int i = tid; i < PB4; i += BLOCK) {
            int4 v = pb4[i];
            int bs[4] = {v.x, v.y, v.z, v.w};
            #pragma unroll
            for (int j = 0; j < 4; ++j) {
                unsigned int d = (unsigned int)(bs[j] - rowBase);
                if (d < (unsigned int)ROWS_PB) {
                    int t = pt[i * 4 + j];
                    float pos = scores[(size_t)(rowBase + d) * NT + t];
                    #pragma unroll
                    for (int q = 0; q < 5; ++q) {
                        float contrib = MARGIN - (pos - stop5[d][q]);
                        c += contrib > 0.0f ? contrib : 0.0f;
                    }
                    int nn = snn[d];
                    valid += (unsigned int)(nn < 5 ? nn : 5);
                }
            }
        }
    }

    #pragma unroll
    for (int off = 32; off >= 1; off >>= 1) {
        c     += __shfl_xor(c, off);
        valid += __shfl_xor(valid, off);
    }
    if ((tid & 63) == 0) { sc[wib] = c; sv[wib] = valid; }
    __syncthreads();

    // ---- Phase 5: FENCE-FREE accumulate + ticket finalize ----
    // All cross-block communication is via device-scope atomics (memory-side
    // RMW). Ordering: the ticket increment consumes the returned old-values
    // of the three accumulating atomics through an opaque v_and (forces
    // vmcnt completion), so a block's partials are globally performed before
    // its ticket increment. No __threadfence -> no per-XCD L2 invalidate
    // storm (R14's 2x slowdown).
    if (tid == 0) {
        float s = 0.0f;
        #pragma unroll
        for (int k = 0; k < ROWS_PB; ++k) s += bsq[k];
        float cb = sc[0] + sc[1] + sc[2] + sc[3];
        unsigned int vbu = sv[0] + sv[1] + sv[2] + sv[3];

        float r1 = atomicAdd(sq_total, s);
        float r2 = atomicAdd(rsum, cb);
        unsigned int r3 = atomicAdd(nrp, vbu);
        unsigned int z = __float_as_uint(r1) | __float_as_uint(r2) | r3;
        asm volatile("v_and_b32 %0, 0, %0" : "+v"(z));   // z = 0, dep kept
        unsigned int done = atomicAdd(ticket, 1u + z);
        if (done == NBLOCKS - 1) {
            float sqt = atomicAdd(sq_total, 0.0f);
            float rs  = atomicAdd(rsum, 0.0f);
            unsigned int n = atomicAdd(nrp, 0u);
            float loss = 0.5f * sqt / 2.0e7f;        // NB*NT = 2e7
            if (n > 0) loss += RANK_W * rs / (float)n;
            out[0] = loss;
        }
    }
}

extern "C" void kernel_launch(void* const* d_in, const int* in_sizes, int n_in,
                              void* d_out, int out_size, void* d_ws, size_t ws_size,
                              hipStream_t stream) {
    const float* scores = (const float*)d_in[0];
    const int*   pb     = (const int*)d_in[1];
    const int*   pt     = (const int*)d_in[2];
    float*       out    = (float*)d_out;

    char* ws = (char*)d_ws;
    int*          counts   = (int*)ws;
    float*        sq_total = (float*)(ws + 5000);
    float*        rsum     = (float*)(ws + 5004);
    unsigned int* nrp      = (unsigned int*)(ws + 5008);
    unsigned int* ticket   = (unsigned int*)(ws + 5012);
    int*          lists    = (int*)(ws + 5120);

    zero_ctrl_kernel<<<5, 256, 0, stream>>>((unsigned int*)ws);
    scatter_kernel<<<(P_PAIRS + 255) / 256, 256, 0, stream>>>(pb, pt, counts, lists);
    fused_row_pair_kernel<<<NBLOCKS, BLOCK, 0, stream>>>(
        scores, pb, pt, counts, lists, sq_total, rsum, nrp, ticket, out);
}

// Round 16
// 60.432 us; speedup vs baseline: 1.5476x; 1.5275x over previous
//
#include <hip/hip_runtime.h>
#include <cstdint>
#include <cstddef>

#define NB 20000
#define NT 1000
#define P_PAIRS 50000
#define MARGIN 2.0f
#define RANK_W 0.3f
#define NEG_SENT -1e9f

// K1: unmasked stream. 16 rows/block (16 lanes/row), 1250 blocks.
#define K1_BLOCK 256
#define K1_ROWS 16
#define K1_NBLOCKS (NB / K1_ROWS)     // 1250
// K2: pair scan + fixup. 100 rows/block, 200 blocks.
#define K2_BLOCK 512
#define K2_ROWS 100
#define K2_NBLOCKS (NB / K2_ROWS)     // 200
#define PB4 (P_PAIRS / 4)             // 12500
#define PLIST_CAP 1024
#define MW 33                         // padded mask words per row

// ---------------- workspace layout (bytes) ----------------
// [0,      800000)  float  top10[NB][10]   (K1 writes all, K2 reads)
// [800000, 805000)  float  sqp[1250]       (K1 writes all, K3 reads)
// [805120, 808320)  float4 p2[200]         (K2 writes all, K3 reads)
// No pre-zeroing needed anywhere; no global atomics anywhere.

// ============================================================
// K1: per-row unmasked Σ sigmoid², top-10 values. No labels.
// ============================================================
__global__ __launch_bounds__(K1_BLOCK)
void row_top10_kernel(const float* __restrict__ scores,
                      float* __restrict__ top10w,
                      float* __restrict__ sqp) {
    const int tid  = threadIdx.x;
    const int lane = tid & 63;
    const int wib  = tid >> 6;          // 0..3
    const int grp  = lane >> 4;         // 0..3
    const int gl   = lane & 15;         // 0..15
    const int localRow = wib * 4 + grp; // 0..15
    const int row = blockIdx.x * K1_ROWS + localRow;

    const float4* rowp = reinterpret_cast<const float4*>(scores + (size_t)row * NT);

    float tp[10];
    #pragma unroll
    for (int i = 0; i < 10; ++i) tp[i] = NEG_SENT;
    float sq = 0.0f;

    // sorted-desc bubble insert (all indices compile-time after unroll)
#define P1(xv)                                                       \
    {                                                                \
        float x_ = (xv);                                             \
        float s_ = __builtin_amdgcn_rcpf(1.0f + __expf(-x_));        \
        sq = fmaf(s_, s_, sq);                                       \
        float cur_ = x_;                                             \
        _Pragma("unroll")                                            \
        for (int i_ = 0; i_ < 10; ++i_) {                            \
            float n_ = fmaxf(tp[i_], cur_);                          \
            cur_ = fminf(tp[i_], cur_);                              \
            tp[i_] = n_;                                             \
        }                                                            \
    }
#define P4(v) P1((v).x); P1((v).y); P1((v).z); P1((v).w);

    // 250 float4/row over 16 lanes: k=0..14 uniform, k=15 for gl<10
    {
        float4 v0 = rowp[gl], v1 = rowp[gl + 16], v2 = rowp[gl + 32], v3 = rowp[gl + 48];
        P4(v0); P4(v1); P4(v2); P4(v3);
    }
    {
        float4 v0 = rowp[gl + 64], v1 = rowp[gl + 80], v2 = rowp[gl + 96], v3 = rowp[gl + 112];
        P4(v0); P4(v1); P4(v2); P4(v3);
    }
    {
        float4 v0 = rowp[gl + 128], v1 = rowp[gl + 144], v2 = rowp[gl + 160], v3 = rowp[gl + 176];
        P4(v0); P4(v1); P4(v2); P4(v3);
    }
    {
        float4 v0 = rowp[gl + 192], v1 = rowp[gl + 208], v2 = rowp[gl + 224];
        P4(v0); P4(v1); P4(v2);
    }
    if (gl < 10) {
        float4 v = rowp[gl + 240];
        P4(v);
    }

    // merge sorted-10 lists across the 16-lane group + reduce sq
    #pragma unroll
    for (int off = 8; off >= 1; off >>= 1) {
        sq += __shfl_xor(sq, off, 16);
        float bb[10], cc[10];
        #pragma unroll
        for (int i = 0; i < 10; ++i) bb[i] = __shfl_xor(tp[i], off, 16);
        #pragma unroll
        for (int i = 0; i < 10; ++i) {
            float best = fmaxf(tp[i], bb[i]);
            #pragma unroll
            for (int j = 0; j < i; ++j)
                best = fmaxf(best, fminf(tp[j], bb[i - 1 - j]));
            cc[i] = best;
        }
        #pragma unroll
        for (int i = 0; i < 10; ++i) tp[i] = cc[i];
    }

    if (gl == 0) {
        float* o = top10w + (size_t)row * 10;
        #pragma unroll
        for (int i = 0; i < 10; ++i) o[i] = tp[i];
    }

    __shared__ float bsq[K1_ROWS];
    if (gl == 0) bsq[localRow] = sq;
    __syncthreads();
    if (tid == 0) {
        float s = 0.0f;
        #pragma unroll
        for (int k = 0; k < K1_ROWS; ++k) s += bsq[k];
        sqp[blockIdx.x] = s;
    }
}

// ============================================================
// K2: scan pairs once (200 blocks), build LDS masks, correct sq,
// derive masked top-5 from unmasked top-10, pair contributions.
// ============================================================
__global__ __launch_bounds__(K2_BLOCK)
void fixup_pair_kernel(const float* __restrict__ scores,
                       const int* __restrict__ pb,
                       const int* __restrict__ pt,
                       const float* __restrict__ top10w,
                       float4* __restrict__ p2) {
    const int tid   = threadIdx.x;
    const int rbase = blockIdx.x * K2_ROWS;

    __shared__ unsigned int mask[K2_ROWS * MW];   // 13.2 KB
    __shared__ int   plist[PLIST_CAP];            // 4 KB
    __shared__ int   pcnt;
    __shared__ float stop5[K2_ROWS][5];
    __shared__ int   snn[K2_ROWS];

    // ---- Phase A: zero LDS mask + counter ----
    for (int i = tid; i < K2_ROWS * MW; i += K2_BLOCK) mask[i] = 0u;
    if (tid == 0) pcnt = 0;
    __syncthreads();

    // ---- Phase B: scan all pairs (4-deep batched) ----
    const int4* pb4 = reinterpret_cast<const int4*>(pb);
#define SC4(v, idx)                                                      \
    {                                                                    \
        int bs_[4] = {(v).x, (v).y, (v).z, (v).w};                       \
        _Pragma("unroll")                                                \
        for (int j_ = 0; j_ < 4; ++j_) {                                 \
            unsigned d_ = (unsigned)(bs_[j_] - rbase);                   \
            if (d_ < (unsigned)K2_ROWS) {                                \
                int t_ = pt[(idx) * 4 + j_];                             \
                atomicOr(&mask[d_ * MW + (t_ >> 5)], 1u << (t_ & 31));   \
                int k_ = atomicAdd(&pcnt, 1);                            \
                if (k_ < PLIST_CAP) plist[k_] = ((int)d_ << 10) | t_;    \
            }                                                            \
        }                                                                \
    }
    #pragma unroll 1
    for (int base = tid; base + 1536 < PB4; base += 2048) {
        int4 va = pb4[base], vb = pb4[base + 512], vc = pb4[base + 1024], vd = pb4[base + 1536];
        SC4(va, base); SC4(vb, base + 512); SC4(vc, base + 1024); SC4(vd, base + 1536);
    }
    {
        int idx = 12288 + tid;
        if (idx < PB4) { int4 v = pb4[idx]; SC4(v, idx); }
    }
    __syncthreads();

    // ---- Phase C: per-row fixup (one thread per row) ----
    float sqc = 0.0f;
    if (tid < K2_ROWS) {
        const int r   = tid;
        const int row = rbase + r;
        const float* t10 = top10w + (size_t)row * 10;
        float L[10];
        #pragma unroll
        for (int i = 0; i < 10; ++i) L[i] = t10[i];

        unsigned flags = 0;
        int removed = 0, numpos = 0;
        #pragma unroll 1
        for (int w = 0; w < 32; ++w) {
            unsigned m = mask[r * MW + w];
            numpos += __popc(m);
            while (m) {
                int b = __ffs(m) - 1; m &= m - 1;
                int c = w * 32 + b;
                float v = scores[(size_t)row * NT + c];
                float s = __builtin_amdgcn_rcpf(1.0f + __expf(-v));
                sqc += 1.0f - 2.0f * s;        // (1-s)^2 - s^2
                if (v >= L[9]) {               // may occupy a top-10 slot
                    bool done = false;
                    #pragma unroll
                    for (int i = 0; i < 10; ++i) {
                        if (!done && !((flags >> i) & 1u) && L[i] == v) {
                            flags |= 1u << i; done = true;
                        }
                    }
                    if (done) removed++;
                }
            }
        }
        snn[r] = NT - numpos;

        if (removed <= 5) {
            int cnt = 0;
            #pragma unroll
            for (int i = 0; i < 10; ++i) {
                if (!((flags >> i) & 1u) && cnt < 5) { stop5[r][cnt] = L[i]; cnt++; }
            }
        } else {
            // rare exact fallback: masked rescan of the row (sentinel-init)
            float f0 = NEG_SENT, f1 = NEG_SENT, f2 = NEG_SENT, f3 = NEG_SENT, f4 = NEG_SENT;
            for (int c = 0; c < NT; ++c) {
                if (!((mask[r * MW + (c >> 5)] >> (c & 31)) & 1u)) {
                    float v = scores[(size_t)row * NT + c];
                    float n0 = fmaxf(f0, v), s0 = fminf(f0, v);
                    float n1 = fmaxf(f1, s0), s1 = fminf(f1, s0);
                    float n2 = fmaxf(f2, s1), s2 = fminf(f2, s1);
                    float n3 = fmaxf(f3, s2), s3 = fminf(f3, s2);
                    float n4 = fmaxf(f4, s3);
                    f0 = n0; f1 = n1; f2 = n2; f3 = n3; f4 = n4;
                }
            }
            stop5[r][0] = f0; stop5[r][1] = f1; stop5[r][2] = f2;
            stop5[r][3] = f3; stop5[r][4] = f4;
        }
    }
    __syncthreads();

    // ---- Phase D: pair contributions ----
    float c = 0.0f;
    unsigned valid = 0;
    const int np = pcnt;
    if (np <= PLIST_CAP) {
        for (int k = tid; k < np; k += K2_BLOCK) {
            int e = plist[k];
            int lr = e >> 10, t = e & 1023;
            float pos = scores[(size_t)(rbase + lr) * NT + t];
            #pragma unroll
            for (int q = 0; q < 5; ++q) {
                float con = MARGIN - (pos - stop5[lr][q]);
                c += con > 0.0f ? con : 0.0f;
            }
            int nn = snn[lr];
            valid += (unsigned)(nn < 5 ? nn : 5);
        }
    } else {
        // adversarial-only: rescan pair list for this block's rows
        for (int i = tid; i < PB4; i += K2_BLOCK) {
            int4 v = pb4[i];
            int bs[4] = {v.x, v.y, v.z, v.w};
            #pragma unroll
            for (int j = 0; j < 4; ++j) {
                unsigned d = (unsigned)(bs[j] - rbase);
                if (d < (unsigned)K2_ROWS) {
                    int t = pt[i * 4 + j];
                    float pos = scores[(size_t)(rbase + d) * NT + t];
                    #pragma unroll
                    for (int q = 0; q < 5; ++q) {
                        float con = MARGIN - (pos - stop5[d][q]);
                        c += con > 0.0f ? con : 0.0f;
                    }
                    int nn = snn[d];
                    valid += (unsigned)(nn < 5 ? nn : 5);
                }
            }
        }
    }

    // ---- Phase E: block reduce -> one float4 store (NO atomics) ----
    #pragma unroll
    for (int off = 32; off >= 1; off >>= 1) {
        c     += __shfl_xor(c, off);
        valid += __shfl_xor(valid, off);
        sqc   += __shfl_xor(sqc, off);
    }
    __shared__ float rc[8]; __shared__ unsigned rv[8]; __shared__ float rs[8];
    const int wib = tid >> 6;
    if ((tid & 63) == 0) { rc[wib] = c; rv[wib] = valid; rs[wib] = sqc; }
    __syncthreads();
    if (tid == 0) {
        float cb = 0.0f, sb = 0.0f; unsigned vb = 0;
        #pragma unroll
        for (int w = 0; w < 8; ++w) { cb += rc[w]; vb += rv[w]; sb += rs[w]; }
        p2[blockIdx.x] = make_float4(sb, cb, (float)vb, 0.0f);
    }
}

// ============================================================
// K3: single-block final reduction
// ============================================================
__global__ __launch_bounds__(256)
void finalize_kernel(const float* __restrict__ sqp,
                     const float4* __restrict__ p2,
                     float* __restrict__ out) {
    float sq = 0.0f, sqc = 0.0f, rk = 0.0f, vd = 0.0f;
    for (int i = threadIdx.x; i < K1_NBLOCKS; i += 256) sq += sqp[i];
    for (int i = threadIdx.x; i < K2_NBLOCKS; i += 256) {
        float4 p = p2[i];
        sqc += p.x; rk += p.y; vd += p.z;
    }
    #pragma unroll
    for (int off = 32; off >= 1; off >>= 1) {
        sq  += __shfl_xor(sq, off);
        sqc += __shfl_xor(sqc, off);
        rk  += __shfl_xor(rk, off);
        vd  += __shfl_xor(vd, off);
    }
    __shared__ float a0[4], a1[4], a2[4], a3[4];
    int wib = threadIdx.x >> 6;
    if ((threadIdx.x & 63) == 0) { a0[wib] = sq; a1[wib] = sqc; a2[wib] = rk; a3[wib] = vd; }
    __syncthreads();
    if (threadIdx.x == 0) {
        float t0 = a0[0] + a0[1] + a0[2] + a0[3];
        float t1 = a1[0] + a1[1] + a1[2] + a1[3];
        float t2 = a2[0] + a2[1] + a2[2] + a2[3];
        float t3 = a3[0] + a3[1] + a3[2] + a3[3];
        float loss = 0.5f * (t0 + t1) / 2.0e7f;     // NB*NT = 2e7
        if (t3 > 0.0f) loss += RANK_W * t2 / t3;
        out[0] = loss;
    }
}

extern "C" void kernel_launch(void* const* d_in, const int* in_sizes, int n_in,
                              void* d_out, int out_size, void* d_ws, size_t ws_size,
                              hipStream_t stream) {
    const float* scores = (const float*)d_in[0];
    const int*   pb     = (const int*)d_in[1];
    const int*   pt     = (const int*)d_in[2];
    float*       out    = (float*)d_out;

    char* ws = (char*)d_ws;
    float*  top10w = (float*)ws;
    float*  sqp    = (float*)(ws + 800000);
    float4* p2     = (float4*)(ws + 805120);

    row_top10_kernel<<<K1_NBLOCKS, K1_BLOCK, 0, stream>>>(scores, top10w, sqp);
    fixup_pair_kernel<<<K2_NBLOCKS, K2_BLOCK, 0, stream>>>(scores, pb, pt, top10w, p2);
    finalize_kernel<<<1, 256, 0, stream>>>(sqp, p2, out);
}

// Round 17
// 35.776 us; speedup vs baseline: 2.6142x; 1.6892x over previous
//
#include <hip/hip_runtime.h>
#include <cstdint>
#include <cstddef>

#define NB 20000
#define NT 1000
#define P_PAIRS 50000
#define MARGIN 2.0f
#define RANK_W 0.3f
#define NEG_SENT -1e9f

#define BLOCK 512
#define ROWS_PB 32
#define NBLOCKS (NB / ROWS_PB)      // 625
#define PB4 (P_PAIRS / 4)           // 12500 int4 loads of pair_bacteria
#define PLIST_CAP 512
#define MROW_W 33                   // padded mask words per row

// ---------------- workspace layout ----------------
// [0, 10000) float4 partials[625] -- fully overwritten every call.

// branchless sorted-desc insert of x into (t0>=t1>=t2>=t3>=t4)
#define INSERT5(x)                                        \
    {                                                     \
        float _x = (x);                                   \
        float n0 = fmaxf(t0, _x), s0_ = fminf(t0, _x);    \
        float n1 = fmaxf(t1, s0_), s1_ = fminf(t1, s0_);  \
        float n2 = fmaxf(t2, s1_), s2_ = fminf(t2, s1_);  \
        float n3 = fmaxf(t3, s2_), s3_ = fminf(t3, s2_);  \
        float n4 = fmaxf(t4, s3_);                        \
        t0 = n0; t1 = n1; t2 = n2; t3 = n3; t4 = n4;      \
    }

#define PROC1(xv, lab)                                              \
    {                                                               \
        float _x = (xv);                                            \
        int _lab = (lab);                                           \
        float _s = __builtin_amdgcn_rcpf(1.0f + __expf(-_x));       \
        float _d = (float)_lab - _s;                                \
        sq = fmaf(_d, _d, sq);                                      \
        pcount += _lab;                                             \
        float _xx = _lab ? NEG_SENT : _x;                           \
        INSERT5(_xx);                                               \
    }

#define PROC4(v, bits)                        \
    PROC1((v).x, (int)(((bits) >> 0) & 1u));  \
    PROC1((v).y, (int)(((bits) >> 1) & 1u));  \
    PROC1((v).z, (int)(((bits) >> 2) & 1u));  \
    PROC1((v).w, (int)(((bits) >> 3) & 1u));

// scan-check 4 pair_bacteria entries; on match set LDS mask bit + record pair
#define SCAN4(v, idx)                                                   \
    {                                                                   \
        int _bs[4] = {(v).x, (v).y, (v).z, (v).w};                      \
        _Pragma("unroll")                                               \
        for (int _j = 0; _j < 4; ++_j) {                                \
            unsigned int _d = (unsigned int)(_bs[_j] - rowBase);        \
            if (_d < (unsigned int)ROWS_PB) {                           \
                int _t = pt[(idx) * 4 + _j];                            \
                atomicOr(&smask[_d * MROW_W + (_t >> 5)], 1u << (_t & 31)); \
                int _k = atomicAdd(&pcnt, 1);                           \
                if (_k < PLIST_CAP) plist[_k] = ((int)_d << 10) | _t;   \
            }                                                           \
        }                                                               \
    }

// K1: 32 rows per 512-thread block (625 blocks). LDS mask from pair scan;
// then row pass + local pair contribs; fence-free float4 partials store.
__global__ __launch_bounds__(BLOCK)
void fused_row_pair_kernel(const float* __restrict__ scores,
                           const int* __restrict__ pb,
                           const int* __restrict__ pt,
                           float4* __restrict__ partials) {
    const int tid  = threadIdx.x;
    const int lane = tid & 63;
    const int wib  = tid >> 6;          // wave in block 0..7
    const int grp  = lane >> 4;         // group in wave  0..3
    const int gl   = lane & 15;         // lane in group  0..15
    const int rowBase = blockIdx.x * ROWS_PB;

    __shared__ unsigned int smask[ROWS_PB * MROW_W];   // 1056 words
    __shared__ float  stop5[ROWS_PB][5];
    __shared__ int    snn[ROWS_PB];
    __shared__ int    plist[PLIST_CAP];
    __shared__ int    pcnt;
    __shared__ float  bsq[ROWS_PB];
    __shared__ float  sc[8];
    __shared__ unsigned int sv[8];

    // ---- Phase 1: zero LDS mask + counter ----
    for (int i = tid; i < ROWS_PB * MROW_W; i += BLOCK) smask[i] = 0u;
    if (tid == 0) pcnt = 0;
    __syncthreads();

    // ---- Phase 2: pair scan (4-deep batched) ----
    const int4* pb4 = reinterpret_cast<const int4*>(pb);
    #pragma unroll 1
    for (int base = tid; base + 1536 < PB4; base += 2048) {
        int4 va = pb4[base       ];
        int4 vb = pb4[base +  512];
        int4 vc = pb4[base + 1024];
        int4 vd = pb4[base + 1536];
        SCAN4(va, base);
        SCAN4(vb, base +  512);
        SCAN4(vc, base + 1024);
        SCAN4(vd, base + 1536);
    }
    {   // tail: indices 12288 .. 12499
        int idx = 12288 + tid;
        if (idx < PB4) {
            int4 v = pb4[idx];
            SCAN4(v, idx);
        }
    }
    __syncthreads();

    // ---- Phase 3: row pass (16 lanes/row; mask from LDS) ----
    const int localRow = wib * 4 + grp;          // 0..31
    const int row = rowBase + localRow;
    const float4* rowp = reinterpret_cast<const float4*>(scores + (size_t)row * NT);
    const unsigned int* mrow = smask + localRow * MROW_W;
    const int wb = gl >> 3;
    const int sh = (gl & 7) * 4;

    float t0 = NEG_SENT, t1 = NEG_SENT, t2 = NEG_SENT, t3 = NEG_SENT, t4 = NEG_SENT;
    float sq = 0.0f;
    int pcount = 0;

    {
        float4 v0  = rowp[gl      ];
        float4 v1  = rowp[gl +  16];
        float4 v2  = rowp[gl +  32];
        float4 v3  = rowp[gl +  48];
        unsigned int b0 = (mrow[wb     ] >> sh) & 0xFu;
        unsigned int b1 = (mrow[wb +  2] >> sh) & 0xFu;
        unsigned int b2 = (mrow[wb +  4] >> sh) & 0xFu;
        unsigned int b3 = (mrow[wb +  6] >> sh) & 0xFu;
        PROC4(v0, b0); PROC4(v1, b1); PROC4(v2, b2); PROC4(v3, b3);
    }
    {
        float4 v0  = rowp[gl +  64];
        float4 v1  = rowp[gl +  80];
        float4 v2  = rowp[gl +  96];
        float4 v3  = rowp[gl + 112];
        unsigned int b0 = (mrow[wb +  8] >> sh) & 0xFu;
        unsigned int b1 = (mrow[wb + 10] >> sh) & 0xFu;
        unsigned int b2 = (mrow[wb + 12] >> sh) & 0xFu;
        unsigned int b3 = (mrow[wb + 14] >> sh) & 0xFu;
        PROC4(v0, b0); PROC4(v1, b1); PROC4(v2, b2); PROC4(v3, b3);
    }
    {
        float4 v0  = rowp[gl + 128];
        float4 v1  = rowp[gl + 144];
        float4 v2  = rowp[gl + 160];
        float4 v3  = rowp[gl + 176];
        unsigned int b0 = (mrow[wb + 16] >> sh) & 0xFu;
        unsigned int b1 = (mrow[wb + 18] >> sh) & 0xFu;
        unsigned int b2 = (mrow[wb + 20] >> sh) & 0xFu;
        unsigned int b3 = (mrow[wb + 22] >> sh) & 0xFu;
        PROC4(v0, b0); PROC4(v1, b1); PROC4(v2, b2); PROC4(v3, b3);
    }
    {
        float4 v0  = rowp[gl + 192];
        float4 v1  = rowp[gl + 208];
        float4 v2  = rowp[gl + 224];
        unsigned int b0 = (mrow[wb + 24] >> sh) & 0xFu;
        unsigned int b1 = (mrow[wb + 26] >> sh) & 0xFu;
        unsigned int b2 = (mrow[wb + 28] >> sh) & 0xFu;
        PROC4(v0, b0); PROC4(v1, b1); PROC4(v2, b2);
    }
    if (gl < 10) {   // k = 15 tail (250 float4 per row)
        float4 v = rowp[gl + 240];
        unsigned int bt = (mrow[wb + 30] >> sh) & 0xFu;
        PROC4(v, bt);
    }

    #pragma unroll
    for (int off = 8; off >= 1; off >>= 1) {
        float b0 = __shfl_xor(t0, off, 16);
        float b1 = __shfl_xor(t1, off, 16);
        float b2 = __shfl_xor(t2, off, 16);
        float b3 = __shfl_xor(t3, off, 16);
        float b4 = __shfl_xor(t4, off, 16);
        sq     += __shfl_xor(sq, off, 16);
        pcount += __shfl_xor(pcount, off, 16);

        float m1  = fminf(t0, b0);
        float m2a = fminf(t1, b0), m2b = fminf(t0, b1);
        float m3a = fminf(t2, b0), m3b = fminf(t1, b1), m3c = fminf(t0, b2);
        float m4a = fminf(t3, b0), m4b = fminf(t2, b1), m4c = fminf(t1, b2), m4d = fminf(t0, b3);
        float c0 = fmaxf(t0, b0);
        float c1 = fmaxf(fmaxf(t1, b1), m1);
        float c2 = fmaxf(fmaxf(t2, b2), fmaxf(m2a, m2b));
        float c3 = fmaxf(fmaxf(t3, b3), fmaxf(fmaxf(m3a, m3b), m3c));
        float c4 = fmaxf(fmaxf(t4, b4), fmaxf(fmaxf(m4a, m4b), fmaxf(m4c, m4d)));
        t0 = c0; t1 = c1; t2 = c2; t3 = c3; t4 = c4;
    }

    if (gl == 0) {
        stop5[localRow][0] = t0; stop5[localRow][1] = t1; stop5[localRow][2] = t2;
        stop5[localRow][3] = t3; stop5[localRow][4] = t4;
        snn[localRow] = NT - pcount;
        bsq[localRow] = sq;
    }
    __syncthreads();

    // ---- Phase 4: this block's pair contributions ----
    float c = 0.0f;
    unsigned int valid = 0;
    int np = pcnt;
    if (np <= PLIST_CAP) {
        for (int k = tid; k < np; k += BLOCK) {
            int e = plist[k];
            int lr = e >> 10, t = e & 1023;
            float pos = scores[(size_t)(rowBase + lr) * NT + t];
            #pragma unroll
            for (int q = 0; q < 5; ++q) {
                float contrib = MARGIN - (pos - stop5[lr][q]);
                c += contrib > 0.0f ? contrib : 0.0f;
            }
            int nn = snn[lr];
            valid += (unsigned int)(nn < 5 ? nn : 5);
        }
    } else {
        // overflow fallback: rescan pair list (never taken for this dataset)
        for (int i = tid; i < PB4; i += BLOCK) {
            int4 v = pb4[i];
            int bs[4] = {v.x, v.y, v.z, v.w};
            #pragma unroll
            for (int j = 0; j < 4; ++j) {
                unsigned int d = (unsigned int)(bs[j] - rowBase);
                if (d < (unsigned int)ROWS_PB) {
                    int t = pt[i * 4 + j];
                    float pos = scores[(size_t)(rowBase + d) * NT + t];
                    #pragma unroll
                    for (int q = 0; q < 5; ++q) {
                        float contrib = MARGIN - (pos - stop5[d][q]);
                        c += contrib > 0.0f ? contrib : 0.0f;
                    }
                    int nn = snn[d];
                    valid += (unsigned int)(nn < 5 ? nn : 5);
                }
            }
        }
    }

    #pragma unroll
    for (int off = 32; off >= 1; off >>= 1) {
        c     += __shfl_xor(c, off);
        valid += __shfl_xor(valid, off);
    }
    if ((tid & 63) == 0) { sc[wib] = c; sv[wib] = valid; }
    __syncthreads();
    if (tid == 0) {
        float s = 0.0f;
        #pragma unroll
        for (int k = 0; k < ROWS_PB; ++k) s += bsq[k];
        float cb = 0.0f;
        float vb = 0.0f;
        #pragma unroll
        for (int w = 0; w < 8; ++w) { cb += sc[w]; vb += (float)sv[w]; }
        partials[blockIdx.x] = make_float4(s, cb, vb, 0.0f);
    }
}

// K2: single-block reduction of 625 partials -> loss
__global__ __launch_bounds__(256)
void finalize_kernel(const float4* __restrict__ partials,
                     float* __restrict__ out) {
    float s = 0.0f, cb = 0.0f, vb = 0.0f;
    for (int i = threadIdx.x; i < NBLOCKS; i += 256) {
        float4 p = partials[i];
        s += p.x; cb += p.y; vb += p.z;
    }
    #pragma unroll
    for (int off = 32; off >= 1; off >>= 1) {
        s  += __shfl_xor(s, off);
        cb += __shfl_xor(cb, off);
        vb += __shfl_xor(vb, off);
    }
    __shared__ float ss[4], scc[4], svv[4];
    int wib = threadIdx.x >> 6;
    if ((threadIdx.x & 63) == 0) { ss[wib] = s; scc[wib] = cb; svv[wib] = vb; }
    __syncthreads();
    if (threadIdx.x == 0) {
        float st = ss[0] + ss[1] + ss[2] + ss[3];
        float ct = scc[0] + scc[1] + scc[2] + scc[3];
        float vt = svv[0] + svv[1] + svv[2] + svv[3];
        float loss = 0.5f * st / 2.0e7f;            // NB*NT = 2e7
        if (vt > 0.0f) loss += RANK_W * ct / vt;
        out[0] = loss;
    }
}

extern "C" void kernel_launch(void* const* d_in, const int* in_sizes, int n_in,
                              void* d_out, int out_size, void* d_ws, size_t ws_size,
                              hipStream_t stream) {
    const float* scores = (const float*)d_in[0];
    const int*   pb     = (const int*)d_in[1];
    const int*   pt     = (const int*)d_in[2];
    float*       out    = (float*)d_out;
    float4*      partials = (float4*)d_ws;

    fused_row_pair_kernel<<<NBLOCKS, BLOCK, 0, stream>>>(scores, pb, pt, partials);
    finalize_kernel<<<1, 256, 0, stream>>>(partials, out);
}